// Round 1
// baseline (339.755 us; speedup 1.0000x reference)
//
#include <hip/hip_runtime.h>
#include <math.h>

#define BATCH    16384
#define MAZE_LEN 3844
#define NCHUNK   961            // MAZE_LEN / 4 float4-chunks per row (exact)
#define ROWS_PER_BLOCK 8
#define NBLK1    (BATCH / ROWS_PER_BLOCK)   // 2048 blocks -> 8 blocks/CU, 32 waves/CU
#define NTERMS   120.0f         // chain has 120 multiplicands (col 3721 twice)

// Math: with p=0, and_f is additive under u(x)=1/x-1, so per row
//   S = sum_i w_i*(1/x_i) - 120;  -log(clamp(1/(1+S), e^-90)) = min(log1p(S), 90)
// where w is the per-column use-count (0/1/2; col 3721 appears twice in chain).
//
// R5 rewrite: the old kernel gathered 120 scattered 4B values/row (~57 distinct
// 64B lines per wave-gather, 13% line utilization) and ran transaction-bound at
// ~0.4-0.8 TB/s effective. This version streams every row fully coalesced
// (dwordx4, 1KB per wave-load) and folds each element through a compile-time
// weight table: BW-bound at ~6 TB/s instead of latency-bound on scatters.

struct WTab { float w[1024][4]; };   // 16 KB, padded chunks 961..1023 are zero

static constexpr WTab make_w() {
    WTab t{};
    int W[MAZE_LEN] = {};
    W[4 * 1 + 124 * 0 + 2]  += 1;    // IDX_A = 6
    W[4 * 29 + 124 * 30 + 3] += 1;   // IDX_B = 3839
    for (int i = 0; i < 31; ++i) { W[124 * i + 1] += 1; W[124 * i + 121] += 1; }
    for (int i = 0; i < 28; ++i) { W[4 * (i + 2) + 1] += 1; W[4 * i + 3721] += 1; }
    // NOTE: 124*30+1 == 4*0+3721 == 3721 -> weight 2 there. Total weight = 120.
    for (int c = 0; c < NCHUNK; ++c)
        for (int j = 0; j < 4; ++j) t.w[c][j] = (float)W[4 * c + j];
    return t;
}

__constant__ WTab c_w = make_w();

// Each block owns 8 consecutive rows. Thread t covers chunks t, t+256, t+512,
// t+768 (chunks >= 961 get weight 0 and a clamped in-bounds address).
// Per element: term = w * rcp(x + B), B = 1e30 iff w==0.
//   - unused elem, any x (incl. 0): 0 * 1e-30 = exactly 0  (no 0*inf NaN)
//   - used elem, x==0: w * inf = inf -> log1p(inf) -> clamped to 90 (matches ref)
//   - rcp(x+1e30)=1e-30 leakage is multiplied by w=0 -> exact; no drift.
__global__ __launch_bounds__(256) void fuzzy_rows(
        const float* __restrict__ maze, float* __restrict__ partial) {
    const int tid  = threadIdx.x;
    const int lane = tid & 63;
    const int wave = tid >> 6;

    float4 w[4], B[4];
    int off[4];
    #pragma unroll
    for (int k = 0; k < 4; ++k) {
        const int c  = tid + (k << 8);
        const int cc = (c < NCHUNK) ? c : (NCHUNK - 1);   // in-bounds address
        off[k] = cc << 2;                                  // float offset in row
        const int wc = (c < NCHUNK) ? c : 1023;            // zero-weight pad
        w[k] = *(const float4*)&c_w.w[wc][0];
        B[k].x = (w[k].x == 0.0f) ? 1e30f : 0.0f;
        B[k].y = (w[k].y == 0.0f) ? 1e30f : 0.0f;
        B[k].z = (w[k].z == 0.0f) ? 1e30f : 0.0f;
        B[k].w = (w[k].w == 0.0f) ? 1e30f : 0.0f;
    }

    __shared__ float s_part[4][ROWS_PER_BLOCK];
    __shared__ float s_fin[ROWS_PER_BLOCK];

    const float* rp = maze + (size_t)blockIdx.x * ROWS_PER_BLOCK * MAZE_LEN;

    for (int r = 0; r < ROWS_PER_BLOCK; ++r, rp += MAZE_LEN) {
        float a0 = 0.0f, a1 = 0.0f, a2 = 0.0f, a3 = 0.0f;  // 4 chains hide rcp/fma latency
        #pragma unroll
        for (int k = 0; k < 4; ++k) {
            const float4 v = *(const float4*)(rp + off[k]);  // coalesced dwordx4
            a0 = fmaf(w[k].x, __builtin_amdgcn_rcpf(v.x + B[k].x), a0);
            a1 = fmaf(w[k].y, __builtin_amdgcn_rcpf(v.y + B[k].y), a1);
            a2 = fmaf(w[k].z, __builtin_amdgcn_rcpf(v.z + B[k].z), a2);
            a3 = fmaf(w[k].w, __builtin_amdgcn_rcpf(v.w + B[k].w), a3);
        }
        float p = (a0 + a1) + (a2 + a3);
        #pragma unroll
        for (int o = 32; o > 0; o >>= 1) p += __shfl_xor(p, o, 64);
        if (lane == 0) s_part[wave][r] = p;   // wave-private slot, no race
    }
    __syncthreads();

    if (tid < ROWS_PER_BLOCK) {
        const float S = s_part[0][tid] + s_part[1][tid]
                      + s_part[2][tid] + s_part[3][tid] - NTERMS;
        s_fin[tid] = fminf(log1pf(S), 90.0f);   // inf -> 90 matches ref clamp
    }
    __syncthreads();

    if (tid == 0) {
        float t = 0.0f;
        #pragma unroll
        for (int r = 0; r < ROWS_PER_BLOCK; ++r) t += s_fin[r];
        partial[blockIdx.x] = t;
    }
}

// Stage 2: single block folds the 2048 per-block sums into the mean.
__global__ __launch_bounds__(256) void reduce_partials(
        const float* __restrict__ partial, float* __restrict__ out) {
    float t = 0.0f;
    #pragma unroll
    for (int i = 0; i < NBLK1 / 256; ++i)
        t += partial[threadIdx.x + (i << 8)];   // coalesced

    #pragma unroll
    for (int o = 32; o > 0; o >>= 1) t += __shfl_xor(t, o, 64);

    __shared__ float s_part[4];
    if ((threadIdx.x & 63) == 0) s_part[threadIdx.x >> 6] = t;
    __syncthreads();

    if (threadIdx.x == 0)
        out[0] = (s_part[0] + s_part[1] + s_part[2] + s_part[3])
                 * (1.0f / (float)BATCH);
}

extern "C" void kernel_launch(void* const* d_in, const int* in_sizes, int n_in,
                              void* d_out, int out_size, void* d_ws, size_t ws_size,
                              hipStream_t stream) {
    const float* maze = (const float*)d_in[0];
    float* out  = (float*)d_out;
    float* part = (float*)d_ws;   // 2048 floats; fully overwritten by K1 each call

    fuzzy_rows<<<dim3(NBLK1), dim3(256), 0, stream>>>(maze, part);
    reduce_partials<<<dim3(1), dim3(256), 0, stream>>>(part, out);
}